// Round 4
// baseline (3519.943 us; speedup 1.0000x reference)
//
#include <hip/hip_runtime.h>
#include <math.h>

typedef unsigned short u16;

// ---------- helpers ----------
static __device__ __forceinline__ float bf2f(u16 u) {
    unsigned v = ((unsigned)u) << 16;
    return __builtin_bit_cast(float, v);
}
// dtype probe: ln_gamma is all-ones. f32 word = 0x3F800000; bf16 pair = 0x3F803F80.
static __device__ __forceinline__ bool is_f32(const void* g) {
    return ((const unsigned*)g)[0] == 0x3F800000u;
}
static __device__ __forceinline__ float ldin(const void* p, size_t i, bool f) {
    return f ? ((const float*)p)[i] : bf2f(((const u16*)p)[i]);
}

// ---------- LayerNorm over D=512 (mode 1: fused embedding gather for vocab slice i=2) ----------
__global__ __launch_bounds__(256) void ln_kernel(
    const float* __restrict__ xin,
    const int* __restrict__ ids, const void* __restrict__ emb, const void* __restrict__ pos,
    const void* __restrict__ gam, const void* __restrict__ bet,
    float* __restrict__ outf, int mode, float* __restrict__ zero8)
{
    __shared__ float red[8];
    bool f = is_f32(gam);
    int row = blockIdx.x, t = threadIdx.x;
    int wid = t >> 6, lane = t & 63;
    float v0, v1;
    if (mode == 1) {
        int id = ids[2 * 8192 + row];                        // ids[2][b][s], row = b*1024+s
        size_t eb = (size_t)(2 * 1024 + id) * 512;           // emb_tables[2][id][:]
        size_t pb = (size_t)(2 * 1024 + (row & 1023)) * 512; // pos_emb[2][s][:]
        v0 = ldin(emb, eb + t, f) + ldin(pos, pb + t, f);
        v1 = ldin(emb, eb + t + 256, f) + ldin(pos, pb + t + 256, f);
    } else {
        v0 = xin[(size_t)row * 512 + t];
        v1 = xin[(size_t)row * 512 + t + 256];
    }
    float s1 = v0 + v1, s2 = v0 * v0 + v1 * v1;
#pragma unroll
    for (int o = 32; o >= 1; o >>= 1) {
        s1 += __shfl_xor(s1, o, 64);
        s2 += __shfl_xor(s2, o, 64);
    }
    if (lane == 0) { red[wid] = s1; red[4 + wid] = s2; }
    __syncthreads();
    float S1 = red[0] + red[1] + red[2] + red[3];
    float S2 = red[4] + red[5] + red[6] + red[7];
    float mu = S1 * (1.f / 512.f);
    float var = fmaxf(S2 * (1.f / 512.f) - mu * mu, 0.f);
    float rs = 1.f / sqrtf(var + 1e-5f);
    outf[(size_t)row * 512 + t] = (v0 - mu) * rs * ldin(gam, t, f) + ldin(bet, t, f);
    outf[(size_t)row * 512 + t + 256] = (v1 - mu) * rs * ldin(gam, t + 256, f) + ldin(bet, t + 256, f);
    if (zero8 && row == 0 && t < 8) zero8[t] = 0.f;
}

// ---------- naive fp32 GEMM: C[m][n] = sum_k A[m][k] * W[k][n], W in native [k][n] layout ----------
// mode 0: C ; mode 1: C+res ; mode 2: relu(C+bias) ; mode 3: C+bias+res
__global__ __launch_bounds__(256) void gemm_naive(
    const float* __restrict__ A, const void* __restrict__ W,
    float* __restrict__ C, const float* __restrict__ res,
    const void* __restrict__ bias, const void* __restrict__ gam, int mode)
{
    __shared__ float sA[8][512];
    bool f = is_f32(gam);
    int t = threadIdx.x;
    int m0 = blockIdx.x * 8;
    for (int idx = t; idx < 4096; idx += 256)
        sA[idx >> 9][idx & 511] = A[(size_t)(m0 + (idx >> 9)) * 512 + (idx & 511)];
    __syncthreads();
    float acc[8][2];
#pragma unroll
    for (int r = 0; r < 8; ++r) { acc[r][0] = 0.f; acc[r][1] = 0.f; }
    for (int k = 0; k < 512; ++k) {
        float w0 = ldin(W, (size_t)k * 512 + t, f);        // coalesced across threads
        float w1 = ldin(W, (size_t)k * 512 + t + 256, f);
#pragma unroll
        for (int r = 0; r < 8; ++r) {                       // sA[r][k]: LDS broadcast
            acc[r][0] += sA[r][k] * w0;
            acc[r][1] += sA[r][k] * w1;
        }
    }
    float b0 = 0.f, b1v = 0.f;
    if (mode >= 2) { b0 = ldin(bias, t, f); b1v = ldin(bias, t + 256, f); }
#pragma unroll
    for (int r = 0; r < 8; ++r) {
        size_t o0 = (size_t)(m0 + r) * 512 + t;
        size_t o1 = o0 + 256;
        float v0 = acc[r][0], v1 = acc[r][1];
        if (mode == 1) { v0 += res[o0]; v1 += res[o1]; }
        else if (mode == 2) { v0 = fmaxf(v0 + b0, 0.f); v1 = fmaxf(v1 + b1v, 0.f); }
        else if (mode == 3) { v0 += b0 + res[o0]; v1 += b1v + res[o1]; }
        C[o0] = v0;
        C[o1] = v1;
    }
}

// ---------- naive retention: one wave per (b,h,n); lane = d in [0,64) ----------
// y[n,d] = sum_{m<=n} gamma^(n-m)/8 * (q_n . k_m) * v[m,d]; then groupnorm(64) and swish(g) gate
__global__ __launch_bounds__(256) void retention_naive(
    const float* __restrict__ Q, const float* __restrict__ K,
    const float* __restrict__ V, const float* __restrict__ G,
    float* __restrict__ Z)
{
    int t = threadIdx.x, wid = t >> 6, d = t & 63;
    int gw = blockIdx.x * 4 + wid;           // [0, 65536)
    int n = gw & 1023, h = (gw >> 10) & 7, b = gw >> 13;
    size_t rowbase = (size_t)(b * 1024 + n) * 512 + h * 64 + d;
    float gamma = 1.f - exp2f(-(float)(5 + h));
    float q = Q[rowbase];
    float y = 0.f, dec = 0.125f;             // 1/sqrt(64) folded: gamma^0 / 8
    size_t off = rowbase;
    for (int m = n; m >= 0; --m, off -= 512) {
        float p = q * K[off];
#pragma unroll
        for (int o = 32; o >= 1; o >>= 1) p += __shfl_xor(p, o, 64);   // q.k over 64 dims
        y += p * dec * V[off];
        dec *= gamma;
    }
    float s1 = y, s2 = y * y;
#pragma unroll
    for (int o = 32; o >= 1; o >>= 1) { s1 += __shfl_xor(s1, o, 64); s2 += __shfl_xor(s2, o, 64); }
    float mu = s1 * (1.f / 64.f);
    float var = fmaxf(s2 * (1.f / 64.f) - mu * mu, 0.f);
    float rs = 1.f / sqrtf(var + 1e-5f);
    float g = G[rowbase];
    float sw = g / (1.f + expf(-g));
    Z[rowbase] = (y - mu) * rs * sw;
}

// ---------- final FC ----------
__global__ __launch_bounds__(256) void fc_partial(const float* __restrict__ x3,
                                                  const void* __restrict__ fcW,
                                                  const void* __restrict__ gam,
                                                  float* __restrict__ logits)
{
    __shared__ float red[4];
    bool f = is_f32(gam);
    int b = blockIdx.x >> 3, sl = blockIdx.x & 7;
    size_t xbase = (size_t)b * 524288 + (size_t)sl * 65536;
    size_t wbase = (size_t)sl * 65536;
    float s = 0.f;
    for (int i = threadIdx.x; i < 16384; i += 256) {
        float4 xv = *(const float4*)&x3[xbase + (size_t)i * 4];
        size_t wi = wbase + (size_t)i * 4;
        s += xv.x * ldin(fcW, wi + 0, f) + xv.y * ldin(fcW, wi + 1, f) +
             xv.z * ldin(fcW, wi + 2, f) + xv.w * ldin(fcW, wi + 3, f);
    }
    int wid = threadIdx.x >> 6, lane = threadIdx.x & 63;
#pragma unroll
    for (int o = 32; o >= 1; o >>= 1) s += __shfl_xor(s, o, 64);
    if (lane == 0) red[wid] = s;
    __syncthreads();
    if (threadIdx.x == 0) atomicAdd(&logits[b], red[0] + red[1] + red[2] + red[3]);
}

// OUTPUT IS FLOAT32: reference returns jax.nn.sigmoid(...) in f32; d_out is float*.
// (Rounds 2/3 wrote bf16 here — f32-decode then saw packed garbage + zeros => absmax 1.0.)
__global__ void fc_final(const float* __restrict__ logits, const void* __restrict__ fcb,
                         const void* __restrict__ gam, float* __restrict__ out)
{
    int t = threadIdx.x;
    bool f = is_f32(gam);
    if (t < 8) {
        float l = logits[t] + ldin(fcb, 0, f);
        out[t] = 1.f / (1.f + expf(-l));
    }
}

extern "C" void kernel_launch(void* const* d_in, const int* in_sizes, int n_in,
                              void* d_out, int out_size, void* d_ws, size_t ws_size,
                              hipStream_t stream)
{
    const int* ids = (const int*)d_in[0];
    const void* emb = d_in[1];
    const void* pos = d_in[2];
    const void* ln_g = d_in[3];
    const void* ln_b = d_in[4];
    const void* Wq = d_in[5];
    const void* Wk = d_in[6];
    const void* Wv = d_in[7];
    const void* Wg = d_in[8];
    const void* Wo = d_in[9];
    const void* W1 = d_in[10];
    const void* b1 = d_in[11];
    const void* W2 = d_in[12];
    const void* b2 = d_in[13];
    const void* fcW = d_in[14];
    const void* fcb = d_in[15];
    float* out = (float*)d_out;

    char* ws = (char*)d_ws;
    const size_t SZ = 16777216;              // 8192 x 512 f32
    float* x0 = (float*)(ws + 0 * SZ);
    float* Qb = (float*)(ws + 1 * SZ);
    float* Kb = (float*)(ws + 2 * SZ);
    float* Vb = (float*)(ws + 3 * SZ);
    float* Gb = (float*)(ws + 4 * SZ);
    float* Z  = (float*)(ws + 5 * SZ);
    float* X1 = (float*)(ws + 6 * SZ);
    float* logits = (float*)(ws + 7 * SZ);   // 32 B; total 117,440,544 B
    float* T  = Qb;   // dead after retention
    float* H  = Kb;
    float* X2 = Vb;
    float* X3 = Gb;

    // only the last vocab iteration (i=2) is live: x is overwritten each pass
    ln_kernel<<<8192, 256, 0, stream>>>(nullptr, ids, emb, pos, ln_g, ln_b, x0, 1, nullptr);
    gemm_naive<<<1024, 256, 0, stream>>>(x0, Wq, Qb, nullptr, nullptr, ln_g, 0);
    gemm_naive<<<1024, 256, 0, stream>>>(x0, Wk, Kb, nullptr, nullptr, ln_g, 0);
    gemm_naive<<<1024, 256, 0, stream>>>(x0, Wv, Vb, nullptr, nullptr, ln_g, 0);
    gemm_naive<<<1024, 256, 0, stream>>>(x0, Wg, Gb, nullptr, nullptr, ln_g, 0);
    retention_naive<<<16384, 256, 0, stream>>>(Qb, Kb, Vb, Gb, Z);
    gemm_naive<<<1024, 256, 0, stream>>>(Z, Wo, X1, x0, nullptr, ln_g, 1);
    ln_kernel<<<8192, 256, 0, stream>>>(X1, nullptr, nullptr, nullptr, ln_g, ln_b, T, 0, nullptr);
    gemm_naive<<<1024, 256, 0, stream>>>(T, W1, H, nullptr, b1, ln_g, 2);
    gemm_naive<<<1024, 256, 0, stream>>>(H, W2, X2, X1, b2, ln_g, 3);
    ln_kernel<<<8192, 256, 0, stream>>>(X2, nullptr, nullptr, nullptr, ln_g, ln_b, X3, 0, logits);
    fc_partial<<<64, 256, 0, stream>>>(X3, fcW, ln_g, logits);
    fc_final<<<1, 64, 0, stream>>>(logits, fcb, ln_g, out);
}

// Round 5
// 489.723 us; speedup vs baseline: 7.1876x; 7.1876x over previous
//
#include <hip/hip_runtime.h>
#include <math.h>

typedef unsigned short u16;
typedef __attribute__((ext_vector_type(8))) short short8;
typedef __attribute__((ext_vector_type(4))) float f32x4;

// Inputs confirmed f32 (round-1 NaN on bf16 reads + round-4 pass on f32 reads).
// Output confirmed f32 (round-4 pass).

// ---------- bf16 helpers ----------
static __device__ __forceinline__ float bf2f(u16 u) {
    unsigned v = ((unsigned)u) << 16;
    return __builtin_bit_cast(float, v);
}
static __device__ __forceinline__ u16 f2bf(float f) {
    unsigned x = __builtin_bit_cast(unsigned, f);
    unsigned r = x + 0x7fffu + ((x >> 16) & 1u);
    return (u16)(r >> 16);
}
static __device__ __forceinline__ void splitbf(float f, u16 &hi, u16 &lo) {
    hi = f2bf(f);
    lo = f2bf(f - bf2f(hi));
}

// ---------- weight transpose+split: WTh/WTl[w][n][k] = split(W[w][k][n]) ----------
// slot order: Wq,Wk,Wv,Wg (packed N=2048 for fused QKVG GEMM), Wo, W1, W2
__global__ __launch_bounds__(256) void transpose_w(
    const float* __restrict__ Wq, const float* __restrict__ Wk, const float* __restrict__ Wv,
    const float* __restrict__ Wg, const float* __restrict__ Wo, const float* __restrict__ W1,
    const float* __restrict__ W2, u16* __restrict__ WTh, u16* __restrict__ WTl)
{
    __shared__ float tile[64][65];
    const float* Ws[7] = {Wq, Wk, Wv, Wg, Wo, W1, W2};
    int w = blockIdx.z;
    int k0 = blockIdx.x * 64, n0 = blockIdx.y * 64;
    const float* W = Ws[w];
    int t = threadIdx.x;
    for (int c = t; c < 4096; c += 256) {
        int row = c >> 6, col = c & 63;   // row=k-local, col=n-local
        tile[row][col] = W[(size_t)(k0 + row) * 512 + n0 + col];
    }
    __syncthreads();
    for (int c = t; c < 4096; c += 256) {
        int row = c >> 6, col = c & 63;   // row=n-local, col=k-local
        u16 hi, lo;
        splitbf(tile[col][row], hi, lo);
        size_t o = (size_t)w * 262144 + (size_t)(n0 + row) * 512 + k0 + col;
        WTh[o] = hi;
        WTl[o] = lo;
    }
}

// ---------- LayerNorm over D=512 (mode 1: fused embedding gather, vocab slice i=2) ----------
__global__ __launch_bounds__(256) void ln_kernel(
    const float* __restrict__ xin,
    const int* __restrict__ ids, const float* __restrict__ emb, const float* __restrict__ pos,
    const float* __restrict__ gam, const float* __restrict__ bet,
    float* __restrict__ outf, int mode, float* __restrict__ zero8)
{
    __shared__ float red[8];
    int row = blockIdx.x, t = threadIdx.x;
    int wid = t >> 6, lane = t & 63;
    float v0, v1;
    if (mode == 1) {
        int id = ids[2 * 8192 + row];                        // ids[2][b][s], row=b*1024+s
        const float* e = emb + (size_t)(2 * 1024 + id) * 512;
        const float* p = pos + (size_t)(2 * 1024 + (row & 1023)) * 512;
        v0 = e[t] + p[t];
        v1 = e[t + 256] + p[t + 256];
    } else {
        v0 = xin[(size_t)row * 512 + t];
        v1 = xin[(size_t)row * 512 + t + 256];
    }
    float s1 = v0 + v1, s2 = v0 * v0 + v1 * v1;
#pragma unroll
    for (int o = 32; o >= 1; o >>= 1) {
        s1 += __shfl_xor(s1, o, 64);
        s2 += __shfl_xor(s2, o, 64);
    }
    if (lane == 0) { red[wid] = s1; red[4 + wid] = s2; }
    __syncthreads();
    float S1 = red[0] + red[1] + red[2] + red[3];
    float S2 = red[4] + red[5] + red[6] + red[7];
    float mu = S1 * (1.f / 512.f);
    float var = fmaxf(S2 * (1.f / 512.f) - mu * mu, 0.f);
    float rs = 1.f / sqrtf(var + 1e-5f);
    outf[(size_t)row * 512 + t] = (v0 - mu) * rs * gam[t] + bet[t];
    outf[(size_t)row * 512 + t + 256] = (v1 - mu) * rs * gam[t + 256] + bet[t + 256];
    if (zero8 && row == 0 && t < 8) zero8[t] = 0.f;
}

// ---------- GEMM: C = A x W^T via split-bf16 MFMA (AhBh + AlBh + AhBl), A f32 ----------
// mode 0: C ; mode 1: C+res ; mode 2: relu(C+bias) ; mode 3: C+bias+res
__global__ __launch_bounds__(256) void gemm_mfma(
    const float* __restrict__ A, const u16* __restrict__ Bhg, const u16* __restrict__ Blg,
    float* __restrict__ C, const float* __restrict__ res, const float* __restrict__ bias,
    int mode, int ostride)
{
    __shared__ u16 Ah[128 * 40];  // stride 40 u16: ds_read_b128 -> 2-way max (free)
    __shared__ u16 Al[128 * 40];
    __shared__ u16 Bh[128 * 40];
    __shared__ u16 Bl[128 * 40];
    int t = threadIdx.x;
    int wid = t >> 6, lane = t & 63, quad = lane >> 4, l15 = lane & 15;
    int wm = wid >> 1, wn = wid & 1;
    int m0 = blockIdx.y * 128, n0 = blockIdx.x * 128;

    f32x4 acc[4][4];
#pragma unroll
    for (int a = 0; a < 4; ++a)
#pragma unroll
        for (int b = 0; b < 4; ++b) acc[a][b] = (f32x4){0.f, 0.f, 0.f, 0.f};

    for (int ki = 0; ki < 16; ++ki) {
        int k0 = ki * 32;
        __syncthreads();
#pragma unroll
        for (int i = 0; i < 2; ++i) {
            int s = t + i * 256;
            int row = s >> 2, part = s & 3;
            const float* ap = &A[(size_t)(m0 + row) * 512 + k0 + part * 8];
            float4 a0 = *(const float4*)ap;
            float4 a1 = *(const float4*)(ap + 4);
            float av[8] = {a0.x, a0.y, a0.z, a0.w, a1.x, a1.y, a1.z, a1.w};
            short8 h8, l8;
#pragma unroll
            for (int j = 0; j < 8; ++j) {
                u16 h, l;
                splitbf(av[j], h, l);
                h8[j] = (short)h;
                l8[j] = (short)l;
            }
            *(short8*)&Ah[row * 40 + part * 8] = h8;
            *(short8*)&Al[row * 40 + part * 8] = l8;
            *(short8*)&Bh[row * 40 + part * 8] =
                *(const short8*)&Bhg[(size_t)(n0 + row) * 512 + k0 + part * 8];
            *(short8*)&Bl[row * 40 + part * 8] =
                *(const short8*)&Blg[(size_t)(n0 + row) * 512 + k0 + part * 8];
        }
        __syncthreads();
        short8 ah[4], al[4], bh[4], bl[4];
#pragma unroll
        for (int tm = 0; tm < 4; ++tm) {
            ah[tm] = *(const short8*)&Ah[(wm * 64 + tm * 16 + l15) * 40 + quad * 8];
            al[tm] = *(const short8*)&Al[(wm * 64 + tm * 16 + l15) * 40 + quad * 8];
        }
#pragma unroll
        for (int tn = 0; tn < 4; ++tn) {
            bh[tn] = *(const short8*)&Bh[(wn * 64 + tn * 16 + l15) * 40 + quad * 8];
            bl[tn] = *(const short8*)&Bl[(wn * 64 + tn * 16 + l15) * 40 + quad * 8];
        }
#pragma unroll
        for (int tm = 0; tm < 4; ++tm)
#pragma unroll
            for (int tn = 0; tn < 4; ++tn) {
                acc[tm][tn] = __builtin_amdgcn_mfma_f32_16x16x32_bf16(ah[tm], bh[tn], acc[tm][tn], 0, 0, 0);
                acc[tm][tn] = __builtin_amdgcn_mfma_f32_16x16x32_bf16(al[tm], bh[tn], acc[tm][tn], 0, 0, 0);
                acc[tm][tn] = __builtin_amdgcn_mfma_f32_16x16x32_bf16(ah[tm], bl[tn], acc[tm][tn], 0, 0, 0);
            }
    }

#pragma unroll
    for (int tm = 0; tm < 4; ++tm) {
#pragma unroll
        for (int tn = 0; tn < 4; ++tn) {
            int n = n0 + wn * 64 + tn * 16 + l15;          // D col = lane&15
            int mbase = m0 + wm * 64 + tm * 16 + quad * 4; // D row = (lane>>4)*4+reg
#pragma unroll
            for (int r = 0; r < 4; ++r) {
                int m = mbase + r;
                float v = acc[tm][tn][r];
                if (mode == 1) v += res[(size_t)m * 512 + n];
                else if (mode == 2) v = fmaxf(v + bias[n], 0.f);
                else if (mode == 3) v += bias[n] + res[(size_t)m * 512 + n];
                C[(size_t)m * ostride + n] = v;
            }
        }
    }
}

// ---------- fused retention: QK^T -> decay -> PV -> groupnorm -> swish gate ----------
// QKVG packed [8192][2048] f32: Q|K|V|G each 512 wide (head h at col h*64).
__global__ __launch_bounds__(256) void retention_mfma(
    const float* __restrict__ QKVG, float* __restrict__ Z)
{
    __shared__ u16 kh[64 * 72], kl[64 * 72];        // k tile [m][d]
    __shared__ u16 vth[64 * 72], vtl[64 * 72];      // v tile transposed [d][m]
    __shared__ u16 ph[4][16 * 72], pl[4][16 * 72];  // per-wave P tile [qrow][m]

    int t = threadIdx.x;
    int wid = t >> 6, lane = t & 63, quad = lane >> 4, l15 = lane & 15;
    int bh = blockIdx.x >> 4;
    int qtr = blockIdx.x & 15;
    int b = bh >> 3, h = bh & 7;
    int qt = (bh & 1) ? (15 - qtr) : qtr;  // load-balance interleave
    int n0 = qt * 64;

    float gamma = 1.f - exp2f(-(float)(5 + h));
    float l2g = log2f(gamma);

    // q fragments: A row i = lane&15, k = (lane>>4)*8+j
    short8 aH[2], aL[2];
    {
        int qrow = b * 1024 + n0 + wid * 16 + l15;
        const float* qp = QKVG + (size_t)qrow * 2048 + h * 64;
#pragma unroll
        for (int ks = 0; ks < 2; ++ks) {
#pragma unroll
            for (int j = 0; j < 8; ++j) {
                float qv = qp[ks * 32 + quad * 8 + j];
                u16 hi, lo;
                splitbf(qv, hi, lo);
                aH[ks][j] = (short)hi;
                aL[ks][j] = (short)lo;
            }
        }
    }

    f32x4 yacc[4];
#pragma unroll
    for (int dt = 0; dt < 4; ++dt) yacc[dt] = (f32x4){0.f, 0.f, 0.f, 0.f};

    for (int mt = 0; mt <= qt; ++mt) {
        __syncthreads();
        for (int c = t; c < 1024; c += 256) {
            int row = c >> 4, c4 = c & 15;
            size_t grow = (size_t)(b * 1024 + mt * 64 + row) * 2048;
            float4 kv = *(const float4*)&QKVG[grow + 512 + h * 64 + c4 * 4];
            u16 hi, lo;
            splitbf(kv.x, hi, lo); kh[row * 72 + c4 * 4 + 0] = hi; kl[row * 72 + c4 * 4 + 0] = lo;
            splitbf(kv.y, hi, lo); kh[row * 72 + c4 * 4 + 1] = hi; kl[row * 72 + c4 * 4 + 1] = lo;
            splitbf(kv.z, hi, lo); kh[row * 72 + c4 * 4 + 2] = hi; kl[row * 72 + c4 * 4 + 2] = lo;
            splitbf(kv.w, hi, lo); kh[row * 72 + c4 * 4 + 3] = hi; kl[row * 72 + c4 * 4 + 3] = lo;
            float4 vv = *(const float4*)&QKVG[grow + 1024 + h * 64 + c4 * 4];
            splitbf(vv.x, hi, lo); vth[(c4 * 4 + 0) * 72 + row] = hi; vtl[(c4 * 4 + 0) * 72 + row] = lo;
            splitbf(vv.y, hi, lo); vth[(c4 * 4 + 1) * 72 + row] = hi; vtl[(c4 * 4 + 1) * 72 + row] = lo;
            splitbf(vv.z, hi, lo); vth[(c4 * 4 + 2) * 72 + row] = hi; vtl[(c4 * 4 + 2) * 72 + row] = lo;
            splitbf(vv.w, hi, lo); vth[(c4 * 4 + 3) * 72 + row] = hi; vtl[(c4 * 4 + 3) * 72 + row] = lo;
        }
        __syncthreads();

        // scores S[16 q-rows][64 m]
        f32x4 sacc[4];
#pragma unroll
        for (int tn = 0; tn < 4; ++tn) sacc[tn] = (f32x4){0.f, 0.f, 0.f, 0.f};
#pragma unroll
        for (int tn = 0; tn < 4; ++tn) {
#pragma unroll
            for (int ks = 0; ks < 2; ++ks) {
                short8 bH = *(const short8*)&kh[(tn * 16 + l15) * 72 + ks * 32 + quad * 8];
                short8 bL = *(const short8*)&kl[(tn * 16 + l15) * 72 + ks * 32 + quad * 8];
                sacc[tn] = __builtin_amdgcn_mfma_f32_16x16x32_bf16(aH[ks], bH, sacc[tn], 0, 0, 0);
                sacc[tn] = __builtin_amdgcn_mfma_f32_16x16x32_bf16(aL[ks], bH, sacc[tn], 0, 0, 0);
                sacc[tn] = __builtin_amdgcn_mfma_f32_16x16x32_bf16(aH[ks], bL, sacc[tn], 0, 0, 0);
            }
        }
        // decay mask -> P (split) through LDS for A-operand layout
#pragma unroll
        for (int tn = 0; tn < 4; ++tn) {
            int mglob = mt * 64 + tn * 16 + l15;           // D col = lane&15
#pragma unroll
            for (int r = 0; r < 4; ++r) {
                int nglob = n0 + wid * 16 + quad * 4 + r;  // D row = quad*4+reg
                int diff = nglob - mglob;
                float p = 0.f;
                if (diff >= 0) p = sacc[tn][r] * exp2f((float)diff * l2g - 3.0f);  // 1/sqrt(64) folded
                u16 hi, lo;
                splitbf(p, hi, lo);
                int off = (quad * 4 + r) * 72 + tn * 16 + l15;
                ph[wid][off] = hi;
                pl[wid][off] = lo;
            }
        }
        __syncthreads();
        // PV: A = P[qrow][m], B = v^T[d][m]
        short8 pH[2], pL[2];
#pragma unroll
        for (int ks = 0; ks < 2; ++ks) {
            pH[ks] = *(const short8*)&ph[wid][l15 * 72 + ks * 32 + quad * 8];
            pL[ks] = *(const short8*)&pl[wid][l15 * 72 + ks * 32 + quad * 8];
        }
#pragma unroll
        for (int dt = 0; dt < 4; ++dt) {
#pragma unroll
            for (int ks = 0; ks < 2; ++ks) {
                short8 vH = *(const short8*)&vth[(dt * 16 + l15) * 72 + ks * 32 + quad * 8];
                short8 vL = *(const short8*)&vtl[(dt * 16 + l15) * 72 + ks * 32 + quad * 8];
                yacc[dt] = __builtin_amdgcn_mfma_f32_16x16x32_bf16(pH[ks], vH, yacc[dt], 0, 0, 0);
                yacc[dt] = __builtin_amdgcn_mfma_f32_16x16x32_bf16(pL[ks], vH, yacc[dt], 0, 0, 0);
                yacc[dt] = __builtin_amdgcn_mfma_f32_16x16x32_bf16(pH[ks], vL, yacc[dt], 0, 0, 0);
            }
        }
    }

    // per-q-row groupnorm over 64 dims + swish gate
#pragma unroll
    for (int r = 0; r < 4; ++r) {
        float s1 = yacc[0][r] + yacc[1][r] + yacc[2][r] + yacc[3][r];
        float s2 = yacc[0][r] * yacc[0][r] + yacc[1][r] * yacc[1][r] +
                   yacc[2][r] * yacc[2][r] + yacc[3][r] * yacc[3][r];
#pragma unroll
        for (int o = 1; o <= 8; o <<= 1) {
            s1 += __shfl_xor(s1, o, 64);
            s2 += __shfl_xor(s2, o, 64);
        }
        float mu = s1 * (1.f / 64.f);
        float var = fmaxf(s2 * (1.f / 64.f) - mu * mu, 0.f);
        float rs = 1.f / sqrtf(var + 1e-5f);
        int nglob = n0 + wid * 16 + quad * 4 + r;
        size_t grow = (size_t)(b * 1024 + nglob);
#pragma unroll
        for (int dt = 0; dt < 4; ++dt) {
            int d = dt * 16 + l15;
            float yv = (yacc[dt][r] - mu) * rs;
            float g = QKVG[grow * 2048 + 1536 + h * 64 + d];
            float sw = g / (1.f + expf(-g));
            Z[grow * 512 + h * 64 + d] = yv * sw;
        }
    }
}

// ---------- final FC ----------
__global__ __launch_bounds__(256) void fc_partial(const float* __restrict__ x3,
                                                  const float* __restrict__ fcW,
                                                  float* __restrict__ logits)
{
    __shared__ float red[4];
    int b = blockIdx.x >> 3, sl = blockIdx.x & 7;
    size_t xbase = (size_t)b * 524288 + (size_t)sl * 65536;
    size_t wbase = (size_t)sl * 65536;
    float s = 0.f;
    for (int i = threadIdx.x; i < 16384; i += 256) {
        float4 xv = *(const float4*)&x3[xbase + (size_t)i * 4];
        float4 wv = *(const float4*)&fcW[wbase + (size_t)i * 4];
        s += xv.x * wv.x + xv.y * wv.y + xv.z * wv.z + xv.w * wv.w;
    }
    int wid = threadIdx.x >> 6, lane = threadIdx.x & 63;
#pragma unroll
    for (int o = 32; o >= 1; o >>= 1) s += __shfl_xor(s, o, 64);
    if (lane == 0) red[wid] = s;
    __syncthreads();
    if (threadIdx.x == 0) atomicAdd(&logits[b], red[0] + red[1] + red[2] + red[3]);
}

__global__ void fc_final(const float* __restrict__ logits, const float* __restrict__ fcb,
                         float* __restrict__ out)
{
    int t = threadIdx.x;
    if (t < 8) {
        float l = logits[t] + fcb[0];
        out[t] = 1.f / (1.f + expf(-l));   // f32 output
    }
}

extern "C" void kernel_launch(void* const* d_in, const int* in_sizes, int n_in,
                              void* d_out, int out_size, void* d_ws, size_t ws_size,
                              hipStream_t stream)
{
    const int* ids = (const int*)d_in[0];
    const float* emb = (const float*)d_in[1];
    const float* pos = (const float*)d_in[2];
    const float* ln_g = (const float*)d_in[3];
    const float* ln_b = (const float*)d_in[4];
    const float* Wq = (const float*)d_in[5];
    const float* Wk = (const float*)d_in[6];
    const float* Wv = (const float*)d_in[7];
    const float* Wg = (const float*)d_in[8];
    const float* Wo = (const float*)d_in[9];
    const float* W1 = (const float*)d_in[10];
    const float* b1 = (const float*)d_in[11];
    const float* W2 = (const float*)d_in[12];
    const float* b2 = (const float*)d_in[13];
    const float* fcW = (const float*)d_in[14];
    const float* fcb = (const float*)d_in[15];
    float* out = (float*)d_out;

    char* ws = (char*)d_ws;
    u16* WTh    = (u16*)(ws);                  //  3,670,016 B
    u16* WTl    = (u16*)(ws + 3670016);        //  3,670,016 B
    float* x0   = (float*)(ws + 7340032);      // 16,777,216 B
    float* QKVG = (float*)(ws + 24117248);     // 67,108,864 B  [8192][2048]
    float* Z    = (float*)(ws + 91226112);     // 16,777,216 B
    float* logits = (float*)(ws + 108003328);  // 32 B  (total 108 MB < 117.4 MB proven OK)
    // QKVG region is dead after retention -> alias the tail activations into it:
    float* X1 = QKVG;
    float* T  = (float*)((char*)QKVG + 16777216);
    float* H  = (float*)((char*)QKVG + 33554432);
    float* X3 = (float*)((char*)QKVG + 50331648);
    float* X2 = x0;   // x0 dead after serving as residual for the Wo GEMM

    // only vocab iteration i=2 is live (x overwritten each pass)
    transpose_w<<<dim3(8, 8, 7), 256, 0, stream>>>(Wq, Wk, Wv, Wg, Wo, W1, W2, WTh, WTl);
    ln_kernel<<<8192, 256, 0, stream>>>(nullptr, ids, emb, pos, ln_g, ln_b, x0, 1, nullptr);
    // fused Q|K|V|G projection: N=2048
    gemm_mfma<<<dim3(16, 64), 256, 0, stream>>>(x0, WTh, WTl, QKVG, nullptr, nullptr, 0, 2048);
    retention_mfma<<<1024, 256, 0, stream>>>(QKVG, Z);
    gemm_mfma<<<dim3(4, 64), 256, 0, stream>>>(Z, WTh + 4 * 262144, WTl + 4 * 262144, X1, x0, nullptr, 1, 512);
    ln_kernel<<<8192, 256, 0, stream>>>(X1, nullptr, nullptr, nullptr, ln_g, ln_b, T, 0, nullptr);
    gemm_mfma<<<dim3(4, 64), 256, 0, stream>>>(T, WTh + 5 * 262144, WTl + 5 * 262144, H, nullptr, b1, 2, 512);
    gemm_mfma<<<dim3(4, 64), 256, 0, stream>>>(H, WTh + 6 * 262144, WTl + 6 * 262144, X2, X1, b2, 3, 512);
    ln_kernel<<<8192, 256, 0, stream>>>(X2, nullptr, nullptr, nullptr, ln_g, ln_b, X3, 0, logits);
    fc_partial<<<64, 256, 0, stream>>>(X3, fcW, logits);
    fc_final<<<1, 64, 0, stream>>>(logits, fcb, out);
}